// Round 6
// baseline (932.663 us; speedup 1.0000x reference)
//
#include <hip/hip_runtime.h>

#define T_DIM 512
#define B_DIM 512
#define OBS_DIM 128
#define H_DIM 128
#define A_DIM 18
#define G3 384
#define LDSS 136        // LDS row stride in halfs (128 + 8 pad, 16B-aligned rows)
#define NPROD 224       // producer blocks (blockIdx 32..255)
#define MAGIC 0x13371337

// exp-argument scales folded into weights/biases/stored gi:
//  r,z gates: arg' = -log2e * arg   (sigmoid(x) = 1/(1+2^(arg')))
//  n gate:    arg' = 2*log2e * arg  (tanh(x) = (2^(arg')-1)/(2^(arg')+1))
#define SC_R (-1.44269504088896f)
#define SC_N (2.88539008177793f)

typedef _Float16 v8h __attribute__((ext_vector_type(8)));
typedef _Float16 v4h __attribute__((ext_vector_type(4)));
typedef float v4f __attribute__((ext_vector_type(4)));

#define EXP2F(x) __builtin_amdgcn_exp2f(x)
#define RCPF(x)  __builtin_amdgcn_rcpf(x)

// LDS-only barrier: drains lgkmcnt but leaves vmcnt in flight.
#define BAR() asm volatile("s_waitcnt lgkmcnt(0)\n\ts_barrier" ::: "memory")

// spin until producer published chunk (relaxed agent-scope; data is at LLC
// before the flag is set, and this XCD has no stale copies of first-touch gi)
__device__ __forceinline__ void waitflag(const int* f) {
    while (__hip_atomic_load(f, __ATOMIC_RELAXED, __HIP_MEMORY_SCOPE_AGENT) != MAGIC)
        __builtin_amdgcn_s_sleep(32);
    asm volatile("" ::: "memory");
}

// ---------------------------------------------------------------------------
// fused: blocks 0..31 = GRU recurrence consumers (16 batch rows each);
//        blocks 32..255 = gi producers (chunk t = p, p+224, p+448).
// gi layout (f16, PRE-SCALED):
//   gRZ[row*256 + w*32 + quad*8 + {0..3: SC_R*r, 4..7: SC_R*z}]
//   gN [row*128 + col] = SC_N * n     (consumer rewrites row t with ys[t])
// ---------------------------------------------------------------------------
__global__ __launch_bounds__(512) void fused(
    const float* __restrict__ hidden,
    const unsigned char* __restrict__ dones_raw,
    const float* __restrict__ obs,
    const float* __restrict__ W_emb,
    const float* __restrict__ b_emb,
    const float* __restrict__ Wi,
    const float* __restrict__ bi,
    const float* __restrict__ Wh,
    const float* __restrict__ bhn,
    _Float16* __restrict__ gRZ,
    _Float16* __restrict__ gN,
    int* __restrict__ flags,
    float* __restrict__ out)
{
    __shared__ __align__(16) char smem[17472];
    const int tid  = threadIdx.x;
    const int lane = tid & 63;
    const int n16  = lane & 15;
    const int quad = lane >> 4;

    if (blockIdx.x >= 32) {
        // ===================== PRODUCER =====================
        _Float16* obs_lds = (_Float16*)smem;                 // 32*LDSS halfs = 8704 B
        _Float16* emb_lds = (_Float16*)(smem + 8704);        // 32*LDSS halfs = 8704 B
        const int cg = tid >> 6;   // wave = col-group
        const int p  = blockIdx.x - 32;

        // A-frags: lane holds A[m=n16][k=kt*32+quad*8+j]; gate scales folded in.
        v8h fe[4];
        v8h fi[3][4];
#pragma unroll
        for (int kt = 0; kt < 4; ++kt)
#pragma unroll
            for (int j = 0; j < 8; ++j) {
                const int k = kt * 32 + quad * 8 + j;
                fe[kt][j] = (_Float16)W_emb[k * H_DIM + cg * 16 + n16];
            }
#pragma unroll
        for (int g = 0; g < 3; ++g) {
            const float sc = (g == 2) ? SC_N : SC_R;
#pragma unroll
            for (int kt = 0; kt < 4; ++kt)
#pragma unroll
                for (int j = 0; j < 8; ++j) {
                    const int k = kt * 32 + quad * 8 + j;
                    fi[g][kt][j] = (_Float16)(Wi[k * G3 + g * H_DIM + cg * 16 + n16] * sc);
                }
        }
        float bemb[4], bir[4], biz[4], bin_[4];
#pragma unroll
        for (int r = 0; r < 4; ++r) {
            const int col = cg * 16 + quad * 4 + r;
            bemb[r] = b_emb[col];
            bir[r]  = bi[col] * SC_R;
            biz[r]  = bi[H_DIM + col] * SC_R;
            bin_[r] = bi[2 * H_DIM + col] * SC_N;
        }

        const int srow = tid >> 4;          // 0..31
        const int sk   = (tid & 15) * 8;    // 0..120

        for (int ci = 0; ci < 3; ++ci) {
            const int t = p + ci * NPROD;
            if (t >= T_DIM) break;
            const int rbase = t * B_DIM;    // 512 rows = 16 iters of M=32

            // stage iter 0's obs
            {
                const float* op = obs + (size_t)(rbase + srow) * OBS_DIM + sk;
                const float4 a = *(const float4*)op;
                const float4 b = *(const float4*)(op + 4);
                v4h pa = { (_Float16)a.x, (_Float16)a.y, (_Float16)a.z, (_Float16)a.w };
                v4h pb = { (_Float16)b.x, (_Float16)b.y, (_Float16)b.z, (_Float16)b.w };
                *(v4h*)&obs_lds[srow * LDSS + sk]     = pa;
                *(v4h*)&obs_lds[srow * LDSS + sk + 4] = pb;
            }
            __syncthreads();

            for (int i = 0; i < 16; ++i) {
                const int row0 = rbase + i * 32;
                const int ni = (i + 1 < 16) ? i + 1 : i;
                const float* opn = obs + (size_t)(rbase + ni * 32 + srow) * OBS_DIM + sk;
                const float4 na = *(const float4*)opn;
                const float4 nb = *(const float4*)(opn + 4);

                // phase A: emb tiles (2 row-tiles x 16 cols)
                v8h bo[2][4];
#pragma unroll
                for (int rt = 0; rt < 2; ++rt)
#pragma unroll
                    for (int kt = 0; kt < 4; ++kt)
                        bo[rt][kt] = *(const v8h*)&obs_lds[(rt * 16 + n16) * LDSS + kt * 32 + quad * 8];
                v4f ea[2] = {{0.f,0.f,0.f,0.f},{0.f,0.f,0.f,0.f}};
#pragma unroll
                for (int rt = 0; rt < 2; ++rt)
#pragma unroll
                    for (int kt = 0; kt < 4; ++kt)
                        ea[rt] = __builtin_amdgcn_mfma_f32_16x16x32_f16(fe[kt], bo[rt][kt], ea[rt], 0, 0, 0);
#pragma unroll
                for (int rt = 0; rt < 2; ++rt) {
                    v4h e;
#pragma unroll
                    for (int r = 0; r < 4; ++r) e[r] = (_Float16)fmaxf(ea[rt][r] + bemb[r], 0.f);
                    *(v4h*)&emb_lds[(rt * 16 + n16) * LDSS + cg * 16 + quad * 4] = e;
                }
                BAR();
                // phase B: gi tiles (2 row-tiles x 3 gates x 16 cols)
                v8h be[2][4];
#pragma unroll
                for (int rt = 0; rt < 2; ++rt)
#pragma unroll
                    for (int kt = 0; kt < 4; ++kt)
                        be[rt][kt] = *(const v8h*)&emb_lds[(rt * 16 + n16) * LDSS + kt * 32 + quad * 8];
                v4f ar[2] = {{0.f,0.f,0.f,0.f},{0.f,0.f,0.f,0.f}};
                v4f az[2] = {{0.f,0.f,0.f,0.f},{0.f,0.f,0.f,0.f}};
                v4f an[2] = {{0.f,0.f,0.f,0.f},{0.f,0.f,0.f,0.f}};
#pragma unroll
                for (int rt = 0; rt < 2; ++rt)
#pragma unroll
                    for (int kt = 0; kt < 4; ++kt) {
                        ar[rt] = __builtin_amdgcn_mfma_f32_16x16x32_f16(fi[0][kt], be[rt][kt], ar[rt], 0, 0, 0);
                        az[rt] = __builtin_amdgcn_mfma_f32_16x16x32_f16(fi[1][kt], be[rt][kt], az[rt], 0, 0, 0);
                        an[rt] = __builtin_amdgcn_mfma_f32_16x16x32_f16(fi[2][kt], be[rt][kt], an[rt], 0, 0, 0);
                    }
#pragma unroll
                for (int rt = 0; rt < 2; ++rt) {
                    const int R = row0 + rt * 16 + n16;
                    v8h rz;
#pragma unroll
                    for (int r = 0; r < 4; ++r) {
                        rz[r]     = (_Float16)(ar[rt][r] + bir[r]);
                        rz[4 + r] = (_Float16)(az[rt][r] + biz[r]);
                    }
                    *(v8h*)&gRZ[(size_t)R * 256 + cg * 32 + quad * 8] = rz;
                    v4h nn;
#pragma unroll
                    for (int r = 0; r < 4; ++r) nn[r] = (_Float16)(an[rt][r] + bin_[r]);
                    *(v4h*)&gN[(size_t)R * 128 + cg * 16 + quad * 4] = nn;
                }
                // stage next iter's obs
                {
                    v4h pa = { (_Float16)na.x, (_Float16)na.y, (_Float16)na.z, (_Float16)na.w };
                    v4h pb = { (_Float16)nb.x, (_Float16)nb.y, (_Float16)nb.z, (_Float16)nb.w };
                    *(v4h*)&obs_lds[srow * LDSS + sk]     = pa;
                    *(v4h*)&obs_lds[srow * LDSS + sk + 4] = pb;
                }
                BAR();
            }
            // publish chunk t: all waves drain own stores at the barrier,
            // fence writes back this XCD's L2, then set the flag (LLC).
            __syncthreads();
            __threadfence();
            if (tid == 0)
                __hip_atomic_store(&flags[t], MAGIC, __ATOMIC_RELEASE, __HIP_MEMORY_SCOPE_AGENT);
        }
        return;
    }

    // ===================== CONSUMER (GRU recurrence) =====================
    _Float16 (*h_lds)[16 * LDSS] = (_Float16(*)[16 * LDSS])smem;   // 2 x 4352 B
    unsigned char* d_lds = (unsigned char*)(smem + 8704);          // 513*16 = 8208 B
    int* bm_p = (int*)(smem + 16912);
    const int w   = tid >> 6;
    const int c16 = w * 16 + quad * 4;
    const int B0  = blockIdx.x * 16;

    if (tid == 0) *bm_p = 0;
    __syncthreads();
    {   // detect dones element width: byte==1 at non-4-aligned offset => 1-byte bools
        int hit = 0;
        for (int i = tid; i < 4096; i += 512)
            if ((i & 3) != 0 && dones_raw[i] == 1) hit = 1;
        if (hit) *bm_p = 1;
    }
    __syncthreads();
    const bool bm = (*bm_p != 0);

    // stage this block's dones slice: d_lds[t*16 + b]; row T zeroed
    {
        if (bm) {
            const int4 v = *(const int4*)(dones_raw + (size_t)tid * B_DIM + B0);
            *(int4*)&d_lds[tid * 16] = v;
        } else {
            const int* di = (const int*)dones_raw;
            const int* pp = di + (size_t)tid * B_DIM + B0;
            int4 wv; unsigned char* wb = (unsigned char*)&wv;
#pragma unroll
            for (int j = 0; j < 16; ++j) wb[j] = (unsigned char)(pp[j] != 0);
            *(int4*)&d_lds[tid * 16] = wv;
        }
        if (tid == 0) { int4 z = {0,0,0,0}; *(int4*)&d_lds[T_DIM * 16] = z; }
    }

    // Wh^T A-frags, gate scales folded in
    v8h fh[3][4];
#pragma unroll
    for (int g = 0; g < 3; ++g) {
        const float sc = (g == 2) ? SC_N : SC_R;
#pragma unroll
        for (int kt = 0; kt < 4; ++kt)
#pragma unroll
            for (int j = 0; j < 8; ++j) {
                const int k = kt * 32 + quad * 8 + j;
                fh[g][kt][j] = (_Float16)(Wh[k * G3 + g * H_DIM + w * 16 + n16] * sc);
            }
    }
    float bhnr[4];
#pragma unroll
    for (int r = 0; r < 4; ++r) bhnr[r] = bhn[c16 + r] * SC_N;

    __syncthreads();   // d_lds visible

    // init carry, pre-masked with done[0]
    const bool d0 = d_lds[n16] != 0;
    float hu[4];
#pragma unroll
    for (int r = 0; r < 4; ++r) {
        const float hv = hidden[(size_t)(B0 + n16) * H_DIM + c16 + r];
        hu[r] = d0 ? 0.f : hv;
    }
    {
        v4h hw = { (_Float16)hu[0], (_Float16)hu[1], (_Float16)hu[2], (_Float16)hu[3] };
        *(v4h*)&h_lds[0][n16 * LDSS + c16] = hw;
    }

    const _Float16* rzp = gRZ + (size_t)(B0 + n16) * 256 + w * 32 + quad * 8;
    _Float16*       np  = gN  + (size_t)(B0 + n16) * 128 + c16;
    const size_t RZT = (size_t)B_DIM * 256;
    const size_t NT  = (size_t)B_DIM * 128;

    // preload t=0,1 (gated on producer flags)
    waitflag(&flags[0]);
    waitflag(&flags[1]);
    v8h s8_0 = *(const v8h*)(rzp);
    v4h s4_0 = *(const v4h*)(np);
    v8h s8_1 = *(const v8h*)(rzp + RZT);
    v4h s4_1 = *(const v4h*)(np + NT);
    __syncthreads();   // h_lds[0] visible

    auto STEP = [&](int t, v8h& s8, v4h& s4, const _Float16* hin, _Float16* hout)
        __attribute__((always_inline)) -> void {
        // gate + issue prefetch for t+2 (2-step cover)
        const int tp = (t + 2 < T_DIM) ? t + 2 : T_DIM - 1;
        waitflag(&flags[tp]);
        const v8h gC8 = *(const v8h*)(rzp + (size_t)tp * RZT);
        const v4h gC4 = *(const v4h*)(np + (size_t)tp * NT);
        const unsigned char dnx = d_lds[(t + 1) * 16 + n16];

        v8h bh[4];
#pragma unroll
        for (int kt = 0; kt < 4; ++kt)
            bh[kt] = *(const v8h*)&hin[n16 * LDSS + kt * 32 + quad * 8];

        v4f ga0 = {0.f,0.f,0.f,0.f}, ga1 = {0.f,0.f,0.f,0.f}, ga2 = {0.f,0.f,0.f,0.f};
#pragma unroll
        for (int kt = 0; kt < 4; ++kt) {
            ga0 = __builtin_amdgcn_mfma_f32_16x16x32_f16(fh[0][kt], bh[kt], ga0, 0, 0, 0);
            ga1 = __builtin_amdgcn_mfma_f32_16x16x32_f16(fh[1][kt], bh[kt], ga1, 0, 0, 0);
            ga2 = __builtin_amdgcn_mfma_f32_16x16x32_f16(fh[2][kt], bh[kt], ga2, 0, 0, 0);
        }

        // fused gates: er=2^sr=e^{-xr}; en=2^sn=e^{2xn}; ez=2^sz=e^{-xz}
        // h = [ez*(en-1) + hu*(en+1)] / [(en+1)*(1+ez)]
        float hn[4];
#pragma unroll
        for (int r = 0; r < 4; ++r) {
            const float er = EXP2F((float)s8[r] + ga0[r]);
            const float rg = RCPF(1.f + er);
            const float sn = fmaf(rg, ga2[r] + bhnr[r], (float)s4[r]);
            const float en = EXP2F(sn);
            const float ez = EXP2F((float)s8[4 + r] + ga1[r]);
            const float enp = en + 1.f;
            const float num = fmaf(hu[r], enp, (en - 1.f) * ez);
            const float den = enp * (1.f + ez);
            hn[r] = num * RCPF(den);
        }

        // ys[t] (unmasked) -> gN row t (consumed >= 2 steps ago)
        v4h yv = { (_Float16)hn[0], (_Float16)hn[1], (_Float16)hn[2], (_Float16)hn[3] };
        *(v4h*)(np + (size_t)t * NT) = yv;

        // mask with done[t+1] at write
        const bool dn = dnx != 0;
        v4h hz = { (_Float16)0.f, (_Float16)0.f, (_Float16)0.f, (_Float16)0.f };
        v4h hv = dn ? hz : yv;
#pragma unroll
        for (int r = 0; r < 4; ++r) hu[r] = dn ? 0.f : hn[r];
        *(v4h*)&hout[n16 * LDSS + c16] = hv;

        s8 = gC8; s4 = gC4;
        BAR();
    };

    for (int t = 0; t < T_DIM; t += 2) {
        STEP(t,     s8_0, s4_0, h_lds[0], h_lds[1]);
        STEP(t + 1, s8_1, s4_1, h_lds[1], h_lds[0]);
    }

    // h_final (hu after t=511 is unmasked: d_lds row 512 zeroed)
#pragma unroll
    for (int r = 0; r < 4; ++r)
        out[(size_t)(B0 + n16) * H_DIM + c16 + r] = hu[r];
}

// ---------------------------------------------------------------------------
// K3: q = ys @ W_out + b_out over all T*B rows. ys = gN (f16).
// 4096 blocks x 256 thr (4 waves x 16 rows). Also overwrites the flag bytes
// at the tail of d_out with real q values.
// ---------------------------------------------------------------------------
__global__ __launch_bounds__(256) void k3_qout(
    const _Float16* __restrict__ ys,
    const float* __restrict__ W_out,
    const float* __restrict__ b_out,
    float* __restrict__ qout)
{
    const int tid  = threadIdx.x;
    const int wv   = tid >> 6;
    const int lane = tid & 63;
    const int n16  = lane & 15;
    const int quad = lane >> 4;
    const int R0   = blockIdx.x * 64 + wv * 16;

    v8h fo[2][4];
#pragma unroll
    for (int ct = 0; ct < 2; ++ct)
#pragma unroll
        for (int kt = 0; kt < 4; ++kt)
#pragma unroll
            for (int j = 0; j < 8; ++j) {
                const int k = kt * 32 + quad * 8 + j;
                const int col = ct * 16 + n16;
                fo[ct][kt][j] = (col < A_DIM) ? (_Float16)W_out[k * A_DIM + col] : (_Float16)0.f;
            }
    float bq0[4], bq1[4];
#pragma unroll
    for (int r = 0; r < 4; ++r) {
        const int c0 = quad * 4 + r;
        const int c1 = 16 + quad * 4 + r;
        bq0[r] = b_out[c0];
        bq1[r] = (c1 < A_DIM) ? b_out[c1] : 0.f;
    }

    v8h by[4];
#pragma unroll
    for (int kt = 0; kt < 4; ++kt)
        by[kt] = *(const v8h*)(ys + (size_t)(R0 + n16) * 128 + kt * 32 + quad * 8);
    v4f q0 = {0.f,0.f,0.f,0.f}, q1 = {0.f,0.f,0.f,0.f};
#pragma unroll
    for (int kt = 0; kt < 4; ++kt) {
        q0 = __builtin_amdgcn_mfma_f32_16x16x32_f16(fo[0][kt], by[kt], q0, 0, 0, 0);
        q1 = __builtin_amdgcn_mfma_f32_16x16x32_f16(fo[1][kt], by[kt], q1, 0, 0, 0);
    }
    float* qp = qout + (size_t)(R0 + n16) * A_DIM;
#pragma unroll
    for (int r = 0; r < 4; ++r) qp[quad * 4 + r] = q0[r] + bq0[r];
    if (quad == 0) {
#pragma unroll
        for (int r = 0; r < 2; ++r) qp[16 + r] = q1[r] + bq1[r];
    }
}

extern "C" void kernel_launch(void* const* d_in, const int* in_sizes, int n_in,
                              void* d_out, int out_size, void* d_ws, size_t ws_size,
                              hipStream_t stream) {
    const float* hidden = (const float*)d_in[0];
    const float* obs    = (const float*)d_in[1];
    const unsigned char* dones = (const unsigned char*)d_in[2];
    const float* W_emb  = (const float*)d_in[3];
    const float* b_emb  = (const float*)d_in[4];
    const float* Wi     = (const float*)d_in[5];
    const float* bi     = (const float*)d_in[6];
    const float* Wh     = (const float*)d_in[7];
    const float* bhn    = (const float*)d_in[8];
    const float* W_out  = (const float*)d_in[9];
    const float* b_out  = (const float*)d_in[10];
    float* out = (float*)d_out;

    _Float16* gRZ = (_Float16*)d_ws;                              // [T*B][256] f16 = 128 MiB
    _Float16* gN  = gRZ + (size_t)T_DIM * B_DIM * 256;            // [T*B][128] f16 =  64 MiB

    // flags: last 512 ints of d_out's q region (poisoned 0xAA != MAGIC each
    // call; overwritten with real q values by k3_qout afterwards)
    int* flags = (int*)(out + (size_t)out_size - 512);

    hipLaunchKernelGGL(fused, dim3(256), dim3(512), 0, stream,
                       hidden, dones, obs, W_emb, b_emb, Wi, bi, Wh, bhn,
                       gRZ, gN, flags, out);
    hipLaunchKernelGGL(k3_qout, dim3(4096), dim3(256), 0, stream,
                       gN, W_out, b_out, out + (size_t)B_DIM * H_DIM);
}